// Round 2
// baseline (260.567 us; speedup 1.0000x reference)
//
#include <hip/hip_runtime.h>
#include <math.h>

typedef __attribute__((ext_vector_type(8))) short short8;
typedef __attribute__((ext_vector_type(4))) float float4v;

#define KDIM  512
#define NQKV  1536

__device__ __forceinline__ unsigned short f2bf(float f) {
    unsigned int u = __float_as_uint(f);
    u += 0x7FFFu + ((u >> 16) & 1u);   // round-to-nearest-even
    return (unsigned short)(u >> 16);
}
__device__ __forceinline__ float bf2f(unsigned short u) {
    return __uint_as_float(((unsigned int)u) << 16);
}

// ---------------- cast x (with roll -32 fused) ----------------
__global__ __launch_bounds__(256) void cast_x_kernel(const float* __restrict__ x,
                                                     unsigned short* __restrict__ xb) {
    int tid = blockIdx.x * 256 + threadIdx.x;
    int t = tid >> 7;               // token row 0..32767 (shifted order)
    int c = (tid & 127) << 2;
    int b = t >> 12, n = t & 4095;
    int src = (b << 12) | ((n + 32) & 4095);    // roll(x, -32)
    float4 v = *(const float4*)(x + (((size_t)src) << 9) + c);
    ushort4 o;
    o.x = f2bf(v.x); o.y = f2bf(v.y); o.z = f2bf(v.z); o.w = f2bf(v.w);
    *(ushort4*)(xb + (((size_t)t) << 9) + c) = o;
}

// ---------------- cast weights ----------------
__global__ __launch_bounds__(256) void cast_w_kernel(const float* __restrict__ wqkv,
                                                     const float* __restrict__ wproj,
                                                     unsigned short* __restrict__ wqkvb,
                                                     unsigned short* __restrict__ wprojb) {
    int tid = blockIdx.x * 256 + threadIdx.x;
    int e = tid << 2;
    if (e < NQKV * KDIM) {
        float4 v = *(const float4*)(wqkv + e);
        ushort4 o; o.x = f2bf(v.x); o.y = f2bf(v.y); o.z = f2bf(v.z); o.w = f2bf(v.w);
        *(ushort4*)(wqkvb + e) = o;
    } else {
        int e2 = e - NQKV * KDIM;
        float4 v = *(const float4*)(wproj + e2);
        ushort4 o; o.x = f2bf(v.x); o.y = f2bf(v.y); o.z = f2bf(v.z); o.w = f2bf(v.w);
        *(ushort4*)(wprojb + e2) = o;
    }
}

// ---------------- GEMM: C[M,N] = A[M,K] @ B[N,K]^T ----------------
template<int N, bool PROJ>
__global__ __launch_bounds__(256, 2) void gemm_kernel(
        const unsigned short* __restrict__ A,
        const unsigned short* __restrict__ B,
        unsigned short* __restrict__ Cb,
        float* __restrict__ Cf,
        const float* __restrict__ bias) {
    __shared__ __align__(16) unsigned short As[128 * 40];
    __shared__ __align__(16) unsigned short Bs[128 * 40];
    const int bn = blockIdx.x, bm = blockIdx.y;
    const int tid = threadIdx.x;
    const int wave = tid >> 6, lane = tid & 63;
    const int quad = lane >> 4, l16 = lane & 15;
    const int wm = (wave >> 1) * 64, wn = (wave & 1) * 64;
    const int r0 = tid >> 2;
    const int c8 = (tid & 3) * 8;

    float4v acc[4][4] = {};

    for (int k0 = 0; k0 < KDIM; k0 += 32) {
        *(short8*)(As + r0 * 40 + c8) =
            *(const short8*)(A + (size_t)(bm * 128 + r0) * KDIM + k0 + c8);
        *(short8*)(As + (r0 + 64) * 40 + c8) =
            *(const short8*)(A + (size_t)(bm * 128 + r0 + 64) * KDIM + k0 + c8);
        *(short8*)(Bs + r0 * 40 + c8) =
            *(const short8*)(B + (size_t)(bn * 128 + r0) * KDIM + k0 + c8);
        *(short8*)(Bs + (r0 + 64) * 40 + c8) =
            *(const short8*)(B + (size_t)(bn * 128 + r0 + 64) * KDIM + k0 + c8);
        __syncthreads();
        short8 af[4], bf[4];
        #pragma unroll
        for (int mi = 0; mi < 4; mi++)
            af[mi] = *(const short8*)(As + (wm + mi * 16 + l16) * 40 + quad * 8);
        #pragma unroll
        for (int ni = 0; ni < 4; ni++)
            bf[ni] = *(const short8*)(Bs + (wn + ni * 16 + l16) * 40 + quad * 8);
        #pragma unroll
        for (int mi = 0; mi < 4; mi++)
            #pragma unroll
            for (int ni = 0; ni < 4; ni++)
                acc[mi][ni] = __builtin_amdgcn_mfma_f32_16x16x32_bf16(
                    af[mi], bf[ni], acc[mi][ni], 0, 0, 0);
        __syncthreads();
    }

    #pragma unroll
    for (int mi = 0; mi < 4; mi++) {
        #pragma unroll
        for (int r = 0; r < 4; r++) {
            int m = bm * 128 + wm + mi * 16 + quad * 4 + r;
            if (!PROJ) {
                #pragma unroll
                for (int ni = 0; ni < 4; ni++) {
                    int n = bn * 128 + wn + ni * 16 + l16;
                    Cb[(size_t)m * N + n] = f2bf(acc[mi][ni][r]);
                }
            } else {
                int b = m >> 12, p = m & 4095;
                int nrow = (p + 32) & 4095;      // roll(out, +32)
                float* orow = Cf + (((size_t)((b << 12) | nrow)) << 9);
                #pragma unroll
                for (int ni = 0; ni < 4; ni++) {
                    int n = bn * 128 + wn + ni * 16 + l16;
                    orow[n] = acc[mi][ni][r] + bias[n];
                }
            }
        }
    }
}

// ---------------- attention: 8x8 attention OVER HEADS per token ----------------
// einsum('bwhd,bwgd->bwhg'): for each (window, position) token, S[h][g] = Q_h . K_g,
// softmax over g (scale 0.125), O[h] = sum_g P[h][g] V[g].
// One thread per (token, head). Block = 128 threads = 16 tokens x 8 heads.
#define TPB_TOK 16
#define LDS_STRIDE 1544   // 1536 + 8: token stride = 3088 B = 772 dw = 4 banks
__global__ __launch_bounds__(128) void attn_kernel(const unsigned short* __restrict__ qkvb,
                                                   unsigned short* __restrict__ aob) {
    __shared__ __align__(16) unsigned short smem[TPB_TOK * LDS_STRIDE];
    const int tid = threadIdx.x;
    const int t0 = blockIdx.x * TPB_TOK;

    // stage 16 qkv rows (16 x 1536 bf16) into LDS, coalesced short8 loads
    {
        int r = tid >> 3, cb = (tid & 7) * 8;
        const unsigned short* src = qkvb + (size_t)(t0 + r) * NQKV;
        unsigned short* dst = smem + r * LDS_STRIDE;
        #pragma unroll
        for (int p = 0; p < 24; p++) {
            int c = cb + p * 64;
            *(short8*)(dst + c) = *(const short8*)(src + c);
        }
    }
    __syncthreads();

    const int tok = tid >> 3, h = tid & 7;
    const unsigned short* row = smem + tok * LDS_STRIDE;

    // Q[h][0..63] -> registers
    float qv[64];
    #pragma unroll
    for (int dc = 0; dc < 8; dc++) {
        short8 qs = *(const short8*)(row + h * 64 + dc * 8);
        #pragma unroll
        for (int j = 0; j < 8; j++)
            qv[dc * 8 + j] = bf2f((unsigned short)qs[j]);
    }

    // S[g] = Q_h . K_g  (K reads are h-independent -> LDS broadcast across 8 lanes)
    float s[8];
    #pragma unroll
    for (int g = 0; g < 8; g++) {
        float acc = 0.f;
        #pragma unroll
        for (int dc = 0; dc < 8; dc++) {
            short8 ks = *(const short8*)(row + 512 + g * 64 + dc * 8);
            #pragma unroll
            for (int j = 0; j < 8; j++)
                acc += qv[dc * 8 + j] * bf2f((unsigned short)ks[j]);
        }
        s[g] = acc;
    }

    // softmax over g with scale 0.125 (scale-after-max == scale-before-max, SC>0)
    float mx = s[0];
    #pragma unroll
    for (int g = 1; g < 8; g++) mx = fmaxf(mx, s[g]);
    float p[8], sum = 0.f;
    #pragma unroll
    for (int g = 0; g < 8; g++) { p[g] = __expf((s[g] - mx) * 0.125f); sum += p[g]; }
    float inv = 1.f / sum;
    #pragma unroll
    for (int g = 0; g < 8; g++) p[g] *= inv;

    // O[d] = sum_g P[g] * V[g][d]
    float o[64];
    #pragma unroll
    for (int j = 0; j < 64; j++) o[j] = 0.f;
    #pragma unroll
    for (int g = 0; g < 8; g++) {
        #pragma unroll
        for (int dc = 0; dc < 8; dc++) {
            short8 vs = *(const short8*)(row + 1024 + g * 64 + dc * 8);
            #pragma unroll
            for (int j = 0; j < 8; j++)
                o[dc * 8 + j] += p[g] * bf2f((unsigned short)vs[j]);
        }
    }

    // scrambled write replicating transpose(0,2,1,3).reshape:
    // proj-in row = win*64 + h*8 + w/8 ; col = (w%8)*64 + d
    int t = t0 + tok, win = t >> 6, w = t & 63;
    unsigned short* dst = aob + (size_t)(win * 64 + h * 8 + (w >> 3)) * 512 + (w & 7) * 64;
    #pragma unroll
    for (int dc = 0; dc < 16; dc++) {
        ushort4 ov;
        ov.x = f2bf(o[dc * 4 + 0]); ov.y = f2bf(o[dc * 4 + 1]);
        ov.z = f2bf(o[dc * 4 + 2]); ov.w = f2bf(o[dc * 4 + 3]);
        *(ushort4*)(dst + dc * 4) = ov;
    }
}

extern "C" void kernel_launch(void* const* d_in, const int* in_sizes, int n_in,
                              void* d_out, int out_size, void* d_ws, size_t ws_size,
                              hipStream_t stream) {
    const float* x      = (const float*)d_in[0];
    const float* w_qkv  = (const float*)d_in[1];
    const float* w_proj = (const float*)d_in[2];
    const float* b_proj = (const float*)d_in[3];
    float* out = (float*)d_out;

    char* ws = (char*)d_ws;
    unsigned short* xb     = (unsigned short*)(ws);                 // 32 MB
    unsigned short* wqkvb  = (unsigned short*)(ws + 33554432);      // 1.5 MB
    unsigned short* wprojb = (unsigned short*)(ws + 35127296);      // 0.5 MB
    unsigned short* qkvb   = (unsigned short*)(ws + 35651584);      // 96 MB
    unsigned short* aob    = (unsigned short*)(ws + 136314880);     // 32 MB

    cast_x_kernel<<<16384, 256, 0, stream>>>(x, xb);
    cast_w_kernel<<<1024, 256, 0, stream>>>(w_qkv, w_proj, wqkvb, wprojb);
    gemm_kernel<NQKV, false><<<dim3(12, 256), 256, 0, stream>>>(xb, wqkvb, qkvb, nullptr, nullptr);
    attn_kernel<<<2048, 128, 0, stream>>>(qkvb, aob);
    gemm_kernel<512, true><<<dim3(4, 256), 256, 0, stream>>>(aob, wprojb, nullptr, out, b_proj);
}

// Round 3
// 257.641 us; speedup vs baseline: 1.0114x; 1.0114x over previous
//
#include <hip/hip_runtime.h>
#include <math.h>

typedef __attribute__((ext_vector_type(8))) short short8;
typedef __attribute__((ext_vector_type(4))) float float4v;

#define KDIM  512
#define NQKV  1536

__device__ __forceinline__ unsigned short f2bf(float f) {
    unsigned int u = __float_as_uint(f);
    u += 0x7FFFu + ((u >> 16) & 1u);   // round-to-nearest-even
    return (unsigned short)(u >> 16);
}
__device__ __forceinline__ float bf2f(unsigned short u) {
    return __uint_as_float(((unsigned int)u) << 16);
}

// async global->LDS DMA, 16 B per lane; LDS dest = wave-uniform base + lane*16
__device__ __forceinline__ void gl2lds16(const unsigned short* g, unsigned short* l) {
    __builtin_amdgcn_global_load_lds(
        (const __attribute__((address_space(1))) void*)g,
        (__attribute__((address_space(3))) void*)l, 16, 0, 0);
}

// ---------------- cast x (with roll -32 fused) ----------------
__global__ __launch_bounds__(256) void cast_x_kernel(const float* __restrict__ x,
                                                     unsigned short* __restrict__ xb) {
    int tid = blockIdx.x * 256 + threadIdx.x;
    int t = tid >> 7;               // token row 0..32767 (shifted order)
    int c = (tid & 127) << 2;
    int b = t >> 12, n = t & 4095;
    int src = (b << 12) | ((n + 32) & 4095);    // roll(x, -32)
    float4 v = *(const float4*)(x + (((size_t)src) << 9) + c);
    ushort4 o;
    o.x = f2bf(v.x); o.y = f2bf(v.y); o.z = f2bf(v.z); o.w = f2bf(v.w);
    *(ushort4*)(xb + (((size_t)t) << 9) + c) = o;
}

// ---------------- cast weights ----------------
__global__ __launch_bounds__(256) void cast_w_kernel(const float* __restrict__ wqkv,
                                                     const float* __restrict__ wproj,
                                                     unsigned short* __restrict__ wqkvb,
                                                     unsigned short* __restrict__ wprojb) {
    int tid = blockIdx.x * 256 + threadIdx.x;
    int e = tid << 2;
    if (e < NQKV * KDIM) {
        float4 v = *(const float4*)(wqkv + e);
        ushort4 o; o.x = f2bf(v.x); o.y = f2bf(v.y); o.z = f2bf(v.z); o.w = f2bf(v.w);
        *(ushort4*)(wqkvb + e) = o;
    } else {
        int e2 = e - NQKV * KDIM;
        float4 v = *(const float4*)(wproj + e2);
        ushort4 o; o.x = f2bf(v.x); o.y = f2bf(v.y); o.z = f2bf(v.z); o.w = f2bf(v.w);
        *(ushort4*)(wprojb + e2) = o;
    }
}

// ---------------- GEMM: C[M,N] = A[M,K] @ B[N,K]^T ----------------
// 128x128 tile, BK=32, 4 waves (2x2). Staging via global_load_lds width=16:
// LDS tiles are flat row-major stride 32 (UNPADDED - DMA requires lane-contiguous).
// Each wave DMAs 1KB chunks: instr j covers chunk (j*4+wave) of 8 (= 16 rows).
template<int N, bool PROJ>
__global__ __launch_bounds__(256, 2) void gemm_kernel(
        const unsigned short* __restrict__ A,
        const unsigned short* __restrict__ B,
        unsigned short* __restrict__ Cb,
        float* __restrict__ Cf,
        const float* __restrict__ bias) {
    __shared__ __align__(16) unsigned short As[128 * 32];
    __shared__ __align__(16) unsigned short Bs[128 * 32];
    const int bn = blockIdx.x, bm = blockIdx.y;
    const int tid = threadIdx.x;
    const int wave = tid >> 6, lane = tid & 63;
    const int quad = lane >> 4, l16 = lane & 15;
    const int wm = (wave >> 1) * 64, wn = (wave & 1) * 64;
    // DMA source row/col for this lane within chunk (j*4+wave):
    const int srow = lane >> 2;          // 0..15 within 16-row chunk
    const int scol = (lane & 3) * 8;     // 8 bf16 = 16 B

    float4v acc[4][4] = {};

    const unsigned short* Abase = A + (size_t)(bm * 128) * KDIM;
    const unsigned short* Bbase = B + (size_t)(bn * 128) * KDIM;

    for (int k0 = 0; k0 < KDIM; k0 += 32) {
        #pragma unroll
        for (int j = 0; j < 2; j++) {
            int chunk = j * 4 + wave;               // 0..7
            int row = chunk * 16 + srow;            // 0..127
            gl2lds16(Abase + (size_t)row * KDIM + k0 + scol, As + chunk * 512);
            gl2lds16(Bbase + (size_t)row * KDIM + k0 + scol, Bs + chunk * 512);
        }
        __syncthreads();
        short8 af[4], bf[4];
        #pragma unroll
        for (int mi = 0; mi < 4; mi++)
            af[mi] = *(const short8*)(As + (wm + mi * 16 + l16) * 32 + quad * 8);
        #pragma unroll
        for (int ni = 0; ni < 4; ni++)
            bf[ni] = *(const short8*)(Bs + (wn + ni * 16 + l16) * 32 + quad * 8);
        #pragma unroll
        for (int mi = 0; mi < 4; mi++)
            #pragma unroll
            for (int ni = 0; ni < 4; ni++)
                acc[mi][ni] = __builtin_amdgcn_mfma_f32_16x16x32_bf16(
                    af[mi], bf[ni], acc[mi][ni], 0, 0, 0);
        __syncthreads();
    }

    #pragma unroll
    for (int mi = 0; mi < 4; mi++) {
        #pragma unroll
        for (int r = 0; r < 4; r++) {
            int m = bm * 128 + wm + mi * 16 + quad * 4 + r;
            if (!PROJ) {
                #pragma unroll
                for (int ni = 0; ni < 4; ni++) {
                    int n = bn * 128 + wn + ni * 16 + l16;
                    Cb[(size_t)m * N + n] = f2bf(acc[mi][ni][r]);
                }
            } else {
                int b = m >> 12, p = m & 4095;
                int nrow = (p + 32) & 4095;      // roll(out, +32)
                float* orow = Cf + (((size_t)((b << 12) | nrow)) << 9);
                #pragma unroll
                for (int ni = 0; ni < 4; ni++) {
                    int n = bn * 128 + wn + ni * 16 + l16;
                    orow[n] = acc[mi][ni][r] + bias[n];
                }
            }
        }
    }
}

// ---------------- attention: 8x8 attention OVER HEADS per token ----------------
// einsum('bwhd,bwgd->bwhg'): per (window,position) token, S[h][g] = Q_h . K_g,
// softmax over g (scale 0.125), O[h] = sum_g P[h][g] V[g].
#define TPB_TOK 16
#define LDS_STRIDE 1544   // 1536 + 8: token stride = 3088 B = 772 dw = 4 banks
__global__ __launch_bounds__(128) void attn_kernel(const unsigned short* __restrict__ qkvb,
                                                   unsigned short* __restrict__ aob) {
    __shared__ __align__(16) unsigned short smem[TPB_TOK * LDS_STRIDE];
    const int tid = threadIdx.x;
    const int t0 = blockIdx.x * TPB_TOK;

    {
        int r = tid >> 3, cb = (tid & 7) * 8;
        const unsigned short* src = qkvb + (size_t)(t0 + r) * NQKV;
        unsigned short* dst = smem + r * LDS_STRIDE;
        #pragma unroll
        for (int p = 0; p < 24; p++) {
            int c = cb + p * 64;
            *(short8*)(dst + c) = *(const short8*)(src + c);
        }
    }
    __syncthreads();

    const int tok = tid >> 3, h = tid & 7;
    const unsigned short* row = smem + tok * LDS_STRIDE;

    float qv[64];
    #pragma unroll
    for (int dc = 0; dc < 8; dc++) {
        short8 qs = *(const short8*)(row + h * 64 + dc * 8);
        #pragma unroll
        for (int j = 0; j < 8; j++)
            qv[dc * 8 + j] = bf2f((unsigned short)qs[j]);
    }

    float s[8];
    #pragma unroll
    for (int g = 0; g < 8; g++) {
        float acc = 0.f;
        #pragma unroll
        for (int dc = 0; dc < 8; dc++) {
            short8 ks = *(const short8*)(row + 512 + g * 64 + dc * 8);
            #pragma unroll
            for (int j = 0; j < 8; j++)
                acc += qv[dc * 8 + j] * bf2f((unsigned short)ks[j]);
        }
        s[g] = acc;
    }

    float mx = s[0];
    #pragma unroll
    for (int g = 1; g < 8; g++) mx = fmaxf(mx, s[g]);
    float p[8], sum = 0.f;
    #pragma unroll
    for (int g = 0; g < 8; g++) { p[g] = __expf((s[g] - mx) * 0.125f); sum += p[g]; }
    float inv = 1.f / sum;
    #pragma unroll
    for (int g = 0; g < 8; g++) p[g] *= inv;

    float o[64];
    #pragma unroll
    for (int j = 0; j < 64; j++) o[j] = 0.f;
    #pragma unroll
    for (int g = 0; g < 8; g++) {
        #pragma unroll
        for (int dc = 0; dc < 8; dc++) {
            short8 vs = *(const short8*)(row + 1024 + g * 64 + dc * 8);
            #pragma unroll
            for (int j = 0; j < 8; j++)
                o[dc * 8 + j] += p[g] * bf2f((unsigned short)vs[j]);
        }
    }

    // scrambled write replicating transpose(0,2,1,3).reshape:
    // proj-in row = win*64 + h*8 + w/8 ; col = (w%8)*64 + d
    int t = t0 + tok, win = t >> 6, w = t & 63;
    unsigned short* dst = aob + (size_t)(win * 64 + h * 8 + (w >> 3)) * 512 + (w & 7) * 64;
    #pragma unroll
    for (int dc = 0; dc < 16; dc++) {
        ushort4 ov;
        ov.x = f2bf(o[dc * 4 + 0]); ov.y = f2bf(o[dc * 4 + 1]);
        ov.z = f2bf(o[dc * 4 + 2]); ov.w = f2bf(o[dc * 4 + 3]);
        *(ushort4*)(dst + dc * 4) = ov;
    }
}

extern "C" void kernel_launch(void* const* d_in, const int* in_sizes, int n_in,
                              void* d_out, int out_size, void* d_ws, size_t ws_size,
                              hipStream_t stream) {
    const float* x      = (const float*)d_in[0];
    const float* w_qkv  = (const float*)d_in[1];
    const float* w_proj = (const float*)d_in[2];
    const float* b_proj = (const float*)d_in[3];
    float* out = (float*)d_out;

    char* ws = (char*)d_ws;
    unsigned short* xb     = (unsigned short*)(ws);                 // 32 MB
    unsigned short* wqkvb  = (unsigned short*)(ws + 33554432);      // 1.5 MB
    unsigned short* wprojb = (unsigned short*)(ws + 35127296);      // 0.5 MB
    unsigned short* qkvb   = (unsigned short*)(ws + 35651584);      // 96 MB
    unsigned short* aob    = (unsigned short*)(ws + 136314880);     // 32 MB

    cast_x_kernel<<<16384, 256, 0, stream>>>(x, xb);
    cast_w_kernel<<<1024, 256, 0, stream>>>(w_qkv, w_proj, wqkvb, wprojb);
    gemm_kernel<NQKV, false><<<dim3(12, 256), 256, 0, stream>>>(xb, wqkvb, qkvb, nullptr, nullptr);
    attn_kernel<<<2048, 128, 0, stream>>>(qkvb, aob);
    gemm_kernel<512, true><<<dim3(4, 256), 256, 0, stream>>>(aob, wprojb, nullptr, out, b_proj);
}

// Round 4
// 251.470 us; speedup vs baseline: 1.0362x; 1.0245x over previous
//
#include <hip/hip_runtime.h>
#include <math.h>

typedef __attribute__((ext_vector_type(8))) short short8;
typedef __attribute__((ext_vector_type(4))) float float4v;

#define KDIM  512
#define NQKV  1536

__device__ __forceinline__ unsigned short f2bf(float f) {
    unsigned int u = __float_as_uint(f);
    u += 0x7FFFu + ((u >> 16) & 1u);   // round-to-nearest-even
    return (unsigned short)(u >> 16);
}
__device__ __forceinline__ float bf2f(unsigned short u) {
    return __uint_as_float(((unsigned int)u) << 16);
}

// async global->LDS DMA, 16 B per lane; LDS dest = wave-uniform base + lane*16
__device__ __forceinline__ void gl2lds16(const unsigned short* g, unsigned short* l) {
    __builtin_amdgcn_global_load_lds(
        (const __attribute__((address_space(1))) void*)g,
        (__attribute__((address_space(3))) void*)l, 16, 0, 0);
}

// ---------------- cast x (with roll -32 fused) ----------------
__global__ __launch_bounds__(256) void cast_x_kernel(const float* __restrict__ x,
                                                     unsigned short* __restrict__ xb) {
    int tid = blockIdx.x * 256 + threadIdx.x;
    int t = tid >> 7;               // token row 0..32767 (shifted order)
    int c = (tid & 127) << 2;
    int b = t >> 12, n = t & 4095;
    int src = (b << 12) | ((n + 32) & 4095);    // roll(x, -32)
    float4 v = *(const float4*)(x + (((size_t)src) << 9) + c);
    ushort4 o;
    o.x = f2bf(v.x); o.y = f2bf(v.y); o.z = f2bf(v.z); o.w = f2bf(v.w);
    *(ushort4*)(xb + (((size_t)t) << 9) + c) = o;
}

// ---------------- cast weights ----------------
__global__ __launch_bounds__(256) void cast_w_kernel(const float* __restrict__ wqkv,
                                                     const float* __restrict__ wproj,
                                                     unsigned short* __restrict__ wqkvb,
                                                     unsigned short* __restrict__ wprojb) {
    int tid = blockIdx.x * 256 + threadIdx.x;
    int e = tid << 2;
    if (e < NQKV * KDIM) {
        float4 v = *(const float4*)(wqkv + e);
        ushort4 o; o.x = f2bf(v.x); o.y = f2bf(v.y); o.z = f2bf(v.z); o.w = f2bf(v.w);
        *(ushort4*)(wqkvb + e) = o;
    } else {
        int e2 = e - NQKV * KDIM;
        float4 v = *(const float4*)(wproj + e2);
        ushort4 o; o.x = f2bf(v.x); o.y = f2bf(v.y); o.z = f2bf(v.z); o.w = f2bf(v.w);
        *(ushort4*)(wprojb + e2) = o;
    }
}

// ---------------- GEMM: C[M,N] = A[M,K] @ B[N,K]^T ----------------
// 128x128 tile, BK=64 (32 MFMA per barrier pair), 4 waves (2x2).
// Staging via global_load_lds width=16 into flat row-major stride-64 LDS with an
// XOR col-block swizzle (applied on the GLOBAL address side, since the DMA's LDS
// destination must be lane-contiguous): stored block p at row r holds source
// col-block p^(r&7). Fragment ds_read_b128 then hits 8 distinct bank groups.
template<int N, bool PROJ>
__global__ __launch_bounds__(256, 2) void gemm_kernel(
        const unsigned short* __restrict__ A,
        const unsigned short* __restrict__ B,
        unsigned short* __restrict__ Cb,
        float* __restrict__ Cf,
        const float* __restrict__ bias) {
    __shared__ __align__(16) unsigned short As[128 * 64];
    __shared__ __align__(16) unsigned short Bs[128 * 64];
    const int bn = blockIdx.x, bm = blockIdx.y;
    const int tid = threadIdx.x;
    const int wave = tid >> 6, lane = tid & 63;
    const int quad = lane >> 4, l16 = lane & 15;
    const int wm = (wave >> 1) * 64, wn = (wave & 1) * 64;
    // DMA: chunk = 8 rows x 64 cols = 1 KB. Lane covers row chunk*8+(lane>>3),
    // stored col-block lane&7, which must hold source col-block (lane&7)^(row&7).
    const int srow = lane >> 3;                  // 0..7 within chunk
    const int scol = ((lane & 7) ^ srow) * 8;    // swizzled source column

    float4v acc[4][4] = {};

    const unsigned short* Abase = A + (size_t)(bm * 128) * KDIM;
    const unsigned short* Bbase = B + (size_t)(bn * 128) * KDIM;

    for (int k0 = 0; k0 < KDIM; k0 += 64) {
        #pragma unroll
        for (int j = 0; j < 4; j++) {
            int chunk = j * 4 + wave;               // 0..15
            int row = chunk * 8 + srow;             // 0..127
            gl2lds16(Abase + (size_t)row * KDIM + k0 + scol, As + chunk * 512);
            gl2lds16(Bbase + (size_t)row * KDIM + k0 + scol, Bs + chunk * 512);
        }
        __syncthreads();
        #pragma unroll
        for (int ki = 0; ki < 2; ki++) {
            short8 af[4], bf[4];
            #pragma unroll
            for (int mi = 0; mi < 4; mi++) {
                int r = wm + mi * 16 + l16;
                int blk = (ki * 4 + quad) ^ (l16 & 7);
                af[mi] = *(const short8*)(As + r * 64 + blk * 8);
            }
            #pragma unroll
            for (int ni = 0; ni < 4; ni++) {
                int r = wn + ni * 16 + l16;
                int blk = (ki * 4 + quad) ^ (l16 & 7);
                bf[ni] = *(const short8*)(Bs + r * 64 + blk * 8);
            }
            #pragma unroll
            for (int mi = 0; mi < 4; mi++)
                #pragma unroll
                for (int ni = 0; ni < 4; ni++)
                    acc[mi][ni] = __builtin_amdgcn_mfma_f32_16x16x32_bf16(
                        af[mi], bf[ni], acc[mi][ni], 0, 0, 0);
        }
        __syncthreads();
    }

    #pragma unroll
    for (int mi = 0; mi < 4; mi++) {
        #pragma unroll
        for (int r = 0; r < 4; r++) {
            int m = bm * 128 + wm + mi * 16 + quad * 4 + r;
            if (!PROJ) {
                #pragma unroll
                for (int ni = 0; ni < 4; ni++) {
                    int n = bn * 128 + wn + ni * 16 + l16;
                    Cb[(size_t)m * N + n] = f2bf(acc[mi][ni][r]);
                }
            } else {
                int b = m >> 12, p = m & 4095;
                int nrow = (p + 32) & 4095;      // roll(out, +32)
                float* orow = Cf + (((size_t)((b << 12) | nrow)) << 9);
                #pragma unroll
                for (int ni = 0; ni < 4; ni++) {
                    int n = bn * 128 + wn + ni * 16 + l16;
                    orow[n] = acc[mi][ni][r] + bias[n];
                }
            }
        }
    }
}

// ---------------- attention: 8x8 attention OVER HEADS per token ----------------
// einsum('bwhd,bwgd->bwhg'): per (window,position) token, S[h][g] = Q_h . K_g,
// softmax over g (scale 0.125), O[h] = sum_g P[h][g] V[g].
// One thread per (token, head); block = 128 threads = 16 tokens x 8 heads.
// Only K,V staged in LDS (padded stride -> conflict-free); Q loaded straight
// to registers from global, issued before staging so the loads overlap.
#define TPB_TOK 16
#define KV_STRIDE 1032   // 1024 + 8: token stride = 2064 B = 516 dw = 4 banks
__global__ __launch_bounds__(128) void attn_kernel(const unsigned short* __restrict__ qkvb,
                                                   unsigned short* __restrict__ aob) {
    __shared__ __align__(16) unsigned short smem[TPB_TOK * KV_STRIDE];
    const int tid = threadIdx.x;
    const int t0 = blockIdx.x * TPB_TOK;
    const int tok = tid >> 3, h = tid & 7;
    const int t = t0 + tok;

    // Q[h][0..63] global loads issue first (overlap with K/V staging)
    short8 qs[8];
    {
        const unsigned short* qsrc = qkvb + (size_t)t * NQKV + h * 64;
        #pragma unroll
        for (int dc = 0; dc < 8; dc++)
            qs[dc] = *(const short8*)(qsrc + dc * 8);
    }

    // stage K,V (rows of 1024 bf16 per token) into LDS, coalesced short8
    {
        int r = tid >> 3, cb = (tid & 7) * 8;
        const unsigned short* src = qkvb + (size_t)(t0 + r) * NQKV + 512;
        unsigned short* dst = smem + r * KV_STRIDE;
        #pragma unroll
        for (int p = 0; p < 16; p++) {
            int c = cb + p * 64;
            *(short8*)(dst + c) = *(const short8*)(src + c);
        }
    }
    __syncthreads();

    const unsigned short* row = smem + tok * KV_STRIDE;

    float qv[64];
    #pragma unroll
    for (int dc = 0; dc < 8; dc++)
        #pragma unroll
        for (int j = 0; j < 8; j++)
            qv[dc * 8 + j] = bf2f((unsigned short)qs[dc][j]);

    // S[g] = Q_h . K_g  (K reads h-independent -> LDS broadcast across 8 lanes)
    float s[8];
    #pragma unroll
    for (int g = 0; g < 8; g++) {
        float acc = 0.f;
        #pragma unroll
        for (int dc = 0; dc < 8; dc++) {
            short8 ks = *(const short8*)(row + g * 64 + dc * 8);
            #pragma unroll
            for (int j = 0; j < 8; j++)
                acc += qv[dc * 8 + j] * bf2f((unsigned short)ks[j]);
        }
        s[g] = acc;
    }

    float mx = s[0];
    #pragma unroll
    for (int g = 1; g < 8; g++) mx = fmaxf(mx, s[g]);
    float p[8], sum = 0.f;
    #pragma unroll
    for (int g = 0; g < 8; g++) { p[g] = __expf((s[g] - mx) * 0.125f); sum += p[g]; }
    float inv = 1.f / sum;
    #pragma unroll
    for (int g = 0; g < 8; g++) p[g] *= inv;

    float o[64];
    #pragma unroll
    for (int j = 0; j < 64; j++) o[j] = 0.f;
    #pragma unroll
    for (int g = 0; g < 8; g++) {
        #pragma unroll
        for (int dc = 0; dc < 8; dc++) {
            short8 vs = *(const short8*)(row + 512 + g * 64 + dc * 8);
            #pragma unroll
            for (int j = 0; j < 8; j++)
                o[dc * 8 + j] += p[g] * bf2f((unsigned short)vs[j]);
        }
    }

    // scrambled write replicating transpose(0,2,1,3).reshape:
    // proj-in row = win*64 + h*8 + w/8 ; col = (w%8)*64 + d
    int win = t >> 6, w = t & 63;
    unsigned short* dst = aob + (size_t)(win * 64 + h * 8 + (w >> 3)) * 512 + (w & 7) * 64;
    #pragma unroll
    for (int dc = 0; dc < 16; dc++) {
        ushort4 ov;
        ov.x = f2bf(o[dc * 4 + 0]); ov.y = f2bf(o[dc * 4 + 1]);
        ov.z = f2bf(o[dc * 4 + 2]); ov.w = f2bf(o[dc * 4 + 3]);
        *(ushort4*)(dst + dc * 4) = ov;
    }
}

extern "C" void kernel_launch(void* const* d_in, const int* in_sizes, int n_in,
                              void* d_out, int out_size, void* d_ws, size_t ws_size,
                              hipStream_t stream) {
    const float* x      = (const float*)d_in[0];
    const float* w_qkv  = (const float*)d_in[1];
    const float* w_proj = (const float*)d_in[2];
    const float* b_proj = (const float*)d_in[3];
    float* out = (float*)d_out;

    char* ws = (char*)d_ws;
    unsigned short* xb     = (unsigned short*)(ws);                 // 32 MB
    unsigned short* wqkvb  = (unsigned short*)(ws + 33554432);      // 1.5 MB
    unsigned short* wprojb = (unsigned short*)(ws + 35127296);      // 0.5 MB
    unsigned short* qkvb   = (unsigned short*)(ws + 35651584);      // 96 MB
    unsigned short* aob    = (unsigned short*)(ws + 136314880);     // 32 MB

    cast_x_kernel<<<16384, 256, 0, stream>>>(x, xb);
    cast_w_kernel<<<1024, 256, 0, stream>>>(w_qkv, w_proj, wqkvb, wprojb);
    gemm_kernel<NQKV, false><<<dim3(12, 256), 256, 0, stream>>>(xb, wqkvb, qkvb, nullptr, nullptr);
    attn_kernel<<<2048, 128, 0, stream>>>(qkvb, aob);
    gemm_kernel<512, true><<<dim3(4, 256), 256, 0, stream>>>(aob, wprojb, nullptr, out, b_proj);
}